// Round 1
// baseline (451.642 us; speedup 1.0000x reference)
//
#include <hip/hip_runtime.h>
#include <hip/hip_bf16.h>

// ODEDriftIntegrator: 24 RHS evals of a 2->64->64->1 tanh MLP per point,
// Dormand-Prince fixed-step (k7 dead: b7=0). Wave handles 16 points via
// mfma_f32_16x16x32_bf16 computing W2^T @ H1^T so point index == lane&15
// for B-operand and D-output alike (no cross-lane layout shuffle needed).
// k-mapping of A/B frags is self-consistent -> correct for any HW kappa.

typedef __attribute__((ext_vector_type(8))) short short8;
typedef __attribute__((ext_vector_type(4))) float f32x4;

#define NPTS   (131072 * 5)
#define NBATCH (NPTS / 16)          // 40960 batches of 16 points
#define LOG2E2 2.8853900817779268f  // 2*log2(e), folded into weights

__device__ __forceinline__ float fexp2(float x) {
#if __has_builtin(__builtin_amdgcn_exp2f)
  return __builtin_amdgcn_exp2f(x);
#else
  return __exp2f(x);
#endif
}
__device__ __forceinline__ float frcp(float x) {
#if __has_builtin(__builtin_amdgcn_rcpf)
  return __builtin_amdgcn_rcpf(x);
#else
  return 1.0f / x;
#endif
}
// tanh(y) given s = 2*log2(e)*y : (e^2y - 1)/(e^2y + 1) = 1 - 2/(t+1)
__device__ __forceinline__ float tanh_pre(float s) {
  float t = fexp2(s);
  return fmaf(-2.0f, frcp(t + 1.0f), 1.0f);
}
__device__ __forceinline__ unsigned pk2bf(float lo, float hi) {
  unsigned r;
  asm("v_cvt_pk_bf16_f32 %0, %1, %2" : "=v"(r) : "v"(lo), "v"(hi));
  return r;
}

union U8 { unsigned u[4]; short8 s; };

__global__ void ode_mfma_kernel(
    const float* __restrict__ sigmap,  // [NPTS,3]
    const float* __restrict__ Wpp,     // [NPTS]
    const float* __restrict__ W1p,     // [2,64]
    const float* __restrict__ b1p,     // [64]
    const float* __restrict__ W2p,     // [64,64]
    const float* __restrict__ b2p,     // [64]
    const float* __restrict__ W3p,     // [64,1]
    const float* __restrict__ b3p,     // [1]
    float* __restrict__ outp)          // [131072]
{
  const int lane = threadIdx.x & 63;
  const int col  = lane & 15;   // point slot within batch (B-col == D-col)
  const int g    = lane >> 4;   // lane group (k-group / D-row group)
  const int wid  = blockIdx.x * (blockDim.x >> 6) + (threadIdx.x >> 6);
  const int nw   = gridDim.x * (blockDim.x >> 6);

  // ---- persistent per-lane constants ----
  // layer1 weights for this lane's B-side hidden set:
  //   e<8 : j = 8g+e  (k-frag 0),  e>=8 : j = 32+8g+(e-8) (k-frag 1)
  float w10[16];
#pragma unroll
  for (int e = 0; e < 16; ++e) {
    int j = (e < 8) ? (8 * g + e) : (32 + 8 * g + (e - 8));
    w10[e] = LOG2E2 * W1p[j];
  }
  // A-frags = W2^T (scaled by LOG2E2), tile t covers out-hidden [16t,16t+16),
  // A-row = col, k element e at group g -> in-hidden kt*32 + 8g + e.
  short8 afr[4][2];
#pragma unroll
  for (int t = 0; t < 4; ++t)
#pragma unroll
    for (int kt = 0; kt < 2; ++kt) {
      U8 tmp;
#pragma unroll
      for (int ee = 0; ee < 4; ++ee) {
        int k0 = kt * 32 + 8 * g + 2 * ee;
        float f0 = LOG2E2 * W2p[(k0)     * 64 + 16 * t + col];
        float f1 = LOG2E2 * W2p[(k0 + 1) * 64 + 16 * t + col];
        tmp.u[ee] = pk2bf(f0, f1);
      }
      afr[t][kt] = tmp.s;
    }
  // D-side constants: lane holds out-hidden j = 16t + 4g + r
  float bb2v[16], w3v[16];
#pragma unroll
  for (int t = 0; t < 4; ++t)
#pragma unroll
    for (int r = 0; r < 4; ++r) {
      int j = 16 * t + 4 * g + r;
      bb2v[4 * t + r] = LOG2E2 * b2p[j];
      w3v[4 * t + r]  = W3p[j];
    }
  const float b3v = b3p[0];

  // DP coefficients (h pre-multiplied)
  const float h   = 0.0025f;
  const float c21 = h * (1.0f / 5.0f);
  const float c31 = h * (3.0f / 40.0f),      c32 = h * (9.0f / 40.0f);
  const float c41 = h * (44.0f / 45.0f),     c42 = -h * (56.0f / 15.0f),    c43 = h * (32.0f / 9.0f);
  const float c51 = h * (19372.0f / 6561.0f), c52 = -h * (25360.0f / 2187.0f),
              c53 = h * (64448.0f / 6561.0f), c54 = -h * (212.0f / 729.0f);
  const float c61 = h * (9017.0f / 3168.0f),  c62 = -h * (355.0f / 33.0f),
              c63 = h * (46732.0f / 5247.0f), c64 = h * (49.0f / 176.0f),   c65 = -h * (5103.0f / 18656.0f);
  const float d1 = h * (35.0f / 384.0f), d3 = h * (500.0f / 1113.0f), d4 = h * (125.0f / 192.0f),
              d5 = -h * (2187.0f / 6784.0f), d6 = h * (11.0f / 84.0f);

  for (int batch = wid; batch < NBATCH; batch += nw) {
    const int p = batch * 16 + col;
    float x           = sigmap[3 * p + 0];
    const float u     = sigmap[3 * p + 1];
    const float wdiff = sigmap[3 * p + 2];

    // cv[e] = LOG2E2 * (u*W1[1][j] + b1[j])  (W1/b1 re-read: L1-resident)
    float cv[16];
#pragma unroll
    for (int e = 0; e < 16; ++e) {
      int j = (e < 8) ? (8 * g + e) : (32 + 8 * g + (e - 8));
      cv[e] = LOG2E2 * fmaf(u, W1p[64 + j], b1p[j]);
    }

    auto rhs = [&](float xi) -> float {
      // layer1: 16 tanh -> two B-frags (H1^T), j per element as in w10[]
      U8 b0, b1f;
#pragma unroll
      for (int ee = 0; ee < 4; ++ee) {
        float t0 = tanh_pre(fmaf(xi, w10[2 * ee],     cv[2 * ee]));
        float t1 = tanh_pre(fmaf(xi, w10[2 * ee + 1], cv[2 * ee + 1]));
        b0.u[ee] = pk2bf(t0, t1);
        float t2 = tanh_pre(fmaf(xi, w10[8 + 2 * ee],     cv[8 + 2 * ee]));
        float t3 = tanh_pre(fmaf(xi, w10[8 + 2 * ee + 1], cv[8 + 2 * ee + 1]));
        b1f.u[ee] = pk2bf(t2, t3);
      }
      // layer2 (MFMA) + layer3 partial dot, all lane-local
      float partial = 0.0f;
#pragma unroll
      for (int t = 0; t < 4; ++t) {
        f32x4 acc = {0.0f, 0.0f, 0.0f, 0.0f};
        acc = __builtin_amdgcn_mfma_f32_16x16x32_bf16(afr[t][0], b0.s,  acc, 0, 0, 0);
        acc = __builtin_amdgcn_mfma_f32_16x16x32_bf16(afr[t][1], b1f.s, acc, 0, 0, 0);
#pragma unroll
        for (int r = 0; r < 4; ++r)
          partial = fmaf(tanh_pre(acc[r] + bb2v[4 * t + r]), w3v[4 * t + r], partial);
      }
      // sum the 4 replica lane-groups (same col, g=0..3)
      partial += __shfl_xor(partial, 16, 64);
      partial += __shfl_xor(partial, 32, 64);
      return partial + b3v;
    };

#pragma unroll 1
    for (int step = 0; step < 4; ++step) {
      float k1 = rhs(x);
      float k2 = rhs(fmaf(c21, k1, x));
      float k3 = rhs(fmaf(c32, k2, fmaf(c31, k1, x)));
      float k4 = rhs(fmaf(c43, k3, fmaf(c42, k2, fmaf(c41, k1, x))));
      float k5 = rhs(fmaf(c54, k4, fmaf(c53, k3, fmaf(c52, k2, fmaf(c51, k1, x)))));
      float k6 = rhs(fmaf(c65, k5, fmaf(c64, k4, fmaf(c63, k3, fmaf(c62, k2, fmaf(c61, k1, x))))));
      x = fmaf(d6, k6, fmaf(d5, k5, fmaf(d4, k4, fmaf(d3, k3, fmaf(d1, k1, x)))));
    }

    x = fmaf(0.01f, wdiff, x);  // diffusion kick: sqrt(2*0.5*sigma^2*dt) = 0.01

    if (lane < 16) {  // one replica writes
      atomicAdd(&outp[p / 5], Wpp[p] * x);
    }
  }
}

extern "C" void kernel_launch(void* const* d_in, const int* in_sizes, int n_in,
                              void* d_out, int out_size, void* d_ws, size_t ws_size,
                              hipStream_t stream) {
  const float* sigmap = (const float*)d_in[0];
  const float* Wpp    = (const float*)d_in[1];
  const float* W1p    = (const float*)d_in[2];
  const float* b1p    = (const float*)d_in[3];
  const float* W2p    = (const float*)d_in[4];
  const float* b2p    = (const float*)d_in[5];
  const float* W3p    = (const float*)d_in[6];
  const float* b3p    = (const float*)d_in[7];
  float* outp = (float*)d_out;

  hipMemsetAsync(outp, 0, (size_t)out_size * sizeof(float), stream);
  ode_mfma_kernel<<<2560, 256, 0, stream>>>(sigmap, Wpp, W1p, b1p, W2p, b2p,
                                            W3p, b3p, outp);
  (void)d_ws; (void)ws_size; (void)n_in; (void)in_sizes;
}

// Round 2
// 397.621 us; speedup vs baseline: 1.1359x; 1.1359x over previous
//
#include <hip/hip_runtime.h>
#include <hip/hip_bf16.h>

// ODEDriftIntegrator: 24 RHS evals of a 2->64->64->1 tanh MLP per point,
// Dormand-Prince fixed-step (k7 dead: b7=0). Wave handles 16 points via
// mfma_f32_16x16x32_bf16 computing W2^T @ H1^T so point index == lane&15
// for B-operand and D-output alike (no cross-lane layout shuffle needed).
//
// R2: tanh via clamped algebraic sigmoid s*rsqrt(1+0.8 s^2) -> 1 trans + 4
// VALU instead of exp2+rcp (2 trans + 2 VALU). Trans pipe (quarter-rate) was
// ~2/3 of issue cycles. Max approx err 0.016; damped by DT=0.01 into output.

typedef __attribute__((ext_vector_type(8))) short short8;
typedef __attribute__((ext_vector_type(4))) float f32x4;

#define NPTS   (131072 * 5)
#define NBATCH (NPTS / 16)          // 40960 batches of 16 points

__device__ __forceinline__ float frsq(float x) {
#if __has_builtin(__builtin_amdgcn_rsqf)
  return __builtin_amdgcn_rsqf(x);
#else
  return __frsqrt_rn(x);
#endif
}
// tanh(s) ~= clamp(s / sqrt(1 + 0.8 s^2), -1, 1); max abs err ~0.016
__device__ __forceinline__ float tanh_cheap(float s) {
  float t = fmaf(0.8f * s, s, 1.0f);
  float y = s * frsq(t);
  return __builtin_amdgcn_fmed3f(y, -1.0f, 1.0f);
}
__device__ __forceinline__ unsigned pk2bf(float lo, float hi) {
  unsigned r;
  asm("v_cvt_pk_bf16_f32 %0, %1, %2" : "=v"(r) : "v"(lo), "v"(hi));
  return r;
}

union U8 { unsigned u[4]; short8 s; };

__global__ void ode_mfma_kernel(
    const float* __restrict__ sigmap,  // [NPTS,3]
    const float* __restrict__ Wpp,     // [NPTS]
    const float* __restrict__ W1p,     // [2,64]
    const float* __restrict__ b1p,     // [64]
    const float* __restrict__ W2p,     // [64,64]
    const float* __restrict__ b2p,     // [64]
    const float* __restrict__ W3p,     // [64,1]
    const float* __restrict__ b3p,     // [1]
    float* __restrict__ outp)          // [131072]
{
  const int lane = threadIdx.x & 63;
  const int col  = lane & 15;   // point slot within batch (B-col == D-col)
  const int g    = lane >> 4;   // lane group (k-group / D-row group)
  const int wid  = blockIdx.x * (blockDim.x >> 6) + (threadIdx.x >> 6);
  const int nw   = gridDim.x * (blockDim.x >> 6);

  // ---- persistent per-lane constants (raw weights, no scaling) ----
  // layer1 weights for this lane's B-side hidden set:
  //   e<8 : j = 8g+e  (k-frag 0),  e>=8 : j = 32+8g+(e-8) (k-frag 1)
  float w10[16];
#pragma unroll
  for (int e = 0; e < 16; ++e) {
    int j = (e < 8) ? (8 * g + e) : (32 + 8 * g + (e - 8));
    w10[e] = W1p[j];
  }
  // A-frags = W2^T, tile t covers out-hidden [16t,16t+16),
  // A-row = col, k element e at group g -> in-hidden kt*32 + 8g + e.
  short8 afr[4][2];
#pragma unroll
  for (int t = 0; t < 4; ++t)
#pragma unroll
    for (int kt = 0; kt < 2; ++kt) {
      U8 tmp;
#pragma unroll
      for (int ee = 0; ee < 4; ++ee) {
        int k0 = kt * 32 + 8 * g + 2 * ee;
        float f0 = W2p[(k0)     * 64 + 16 * t + col];
        float f1 = W2p[(k0 + 1) * 64 + 16 * t + col];
        tmp.u[ee] = pk2bf(f0, f1);
      }
      afr[t][kt] = tmp.s;
    }
  // D-side constants: lane holds out-hidden j = 16t + 4g + r
  float bb2v[16], w3v[16];
#pragma unroll
  for (int t = 0; t < 4; ++t)
#pragma unroll
    for (int r = 0; r < 4; ++r) {
      int j = 16 * t + 4 * g + r;
      bb2v[4 * t + r] = b2p[j];
      w3v[4 * t + r]  = W3p[j];
    }
  const float b3v = b3p[0];

  // DP coefficients (h pre-multiplied)
  const float h   = 0.0025f;
  const float c21 = h * (1.0f / 5.0f);
  const float c31 = h * (3.0f / 40.0f),      c32 = h * (9.0f / 40.0f);
  const float c41 = h * (44.0f / 45.0f),     c42 = -h * (56.0f / 15.0f),    c43 = h * (32.0f / 9.0f);
  const float c51 = h * (19372.0f / 6561.0f), c52 = -h * (25360.0f / 2187.0f),
              c53 = h * (64448.0f / 6561.0f), c54 = -h * (212.0f / 729.0f);
  const float c61 = h * (9017.0f / 3168.0f),  c62 = -h * (355.0f / 33.0f),
              c63 = h * (46732.0f / 5247.0f), c64 = h * (49.0f / 176.0f),   c65 = -h * (5103.0f / 18656.0f);
  const float d1 = h * (35.0f / 384.0f), d3 = h * (500.0f / 1113.0f), d4 = h * (125.0f / 192.0f),
              d5 = -h * (2187.0f / 6784.0f), d6 = h * (11.0f / 84.0f);

  for (int batch = wid; batch < NBATCH; batch += nw) {
    const int p = batch * 16 + col;
    float x           = sigmap[3 * p + 0];
    const float u     = sigmap[3 * p + 1];
    const float wdiff = sigmap[3 * p + 2];

    // cv[e] = u*W1[1][j] + b1[j]  (W1/b1 re-read: L1-resident)
    float cv[16];
#pragma unroll
    for (int e = 0; e < 16; ++e) {
      int j = (e < 8) ? (8 * g + e) : (32 + 8 * g + (e - 8));
      cv[e] = fmaf(u, W1p[64 + j], b1p[j]);
    }

    auto rhs = [&](float xi) -> float {
      // layer1: 16 tanh -> two B-frags (H1^T), j per element as in w10[]
      U8 b0, b1f;
#pragma unroll
      for (int ee = 0; ee < 4; ++ee) {
        float t0 = tanh_cheap(fmaf(xi, w10[2 * ee],     cv[2 * ee]));
        float t1 = tanh_cheap(fmaf(xi, w10[2 * ee + 1], cv[2 * ee + 1]));
        b0.u[ee] = pk2bf(t0, t1);
        float t2 = tanh_cheap(fmaf(xi, w10[8 + 2 * ee],     cv[8 + 2 * ee]));
        float t3 = tanh_cheap(fmaf(xi, w10[8 + 2 * ee + 1], cv[8 + 2 * ee + 1]));
        b1f.u[ee] = pk2bf(t2, t3);
      }
      // layer2 (MFMA) + layer3 partial dot, all lane-local
      float partial = 0.0f;
#pragma unroll
      for (int t = 0; t < 4; ++t) {
        f32x4 acc = {0.0f, 0.0f, 0.0f, 0.0f};
        acc = __builtin_amdgcn_mfma_f32_16x16x32_bf16(afr[t][0], b0.s,  acc, 0, 0, 0);
        acc = __builtin_amdgcn_mfma_f32_16x16x32_bf16(afr[t][1], b1f.s, acc, 0, 0, 0);
#pragma unroll
        for (int r = 0; r < 4; ++r)
          partial = fmaf(tanh_cheap(acc[r] + bb2v[4 * t + r]), w3v[4 * t + r], partial);
      }
      // sum the 4 replica lane-groups (same col, g=0..3)
      partial += __shfl_xor(partial, 16, 64);
      partial += __shfl_xor(partial, 32, 64);
      return partial + b3v;
    };

#pragma unroll 1
    for (int step = 0; step < 4; ++step) {
      float k1 = rhs(x);
      float k2 = rhs(fmaf(c21, k1, x));
      float k3 = rhs(fmaf(c32, k2, fmaf(c31, k1, x)));
      float k4 = rhs(fmaf(c43, k3, fmaf(c42, k2, fmaf(c41, k1, x))));
      float k5 = rhs(fmaf(c54, k4, fmaf(c53, k3, fmaf(c52, k2, fmaf(c51, k1, x)))));
      float k6 = rhs(fmaf(c65, k5, fmaf(c64, k4, fmaf(c63, k3, fmaf(c62, k2, fmaf(c61, k1, x))))));
      x = fmaf(d6, k6, fmaf(d5, k5, fmaf(d4, k4, fmaf(d3, k3, fmaf(d1, k1, x)))));
    }

    x = fmaf(0.01f, wdiff, x);  // diffusion kick: sqrt(2*0.5*sigma^2*dt) = 0.01

    if (lane < 16) {  // one replica writes
      atomicAdd(&outp[p / 5], Wpp[p] * x);
    }
  }
}

extern "C" void kernel_launch(void* const* d_in, const int* in_sizes, int n_in,
                              void* d_out, int out_size, void* d_ws, size_t ws_size,
                              hipStream_t stream) {
  const float* sigmap = (const float*)d_in[0];
  const float* Wpp    = (const float*)d_in[1];
  const float* W1p    = (const float*)d_in[2];
  const float* b1p    = (const float*)d_in[3];
  const float* W2p    = (const float*)d_in[4];
  const float* b2p    = (const float*)d_in[5];
  const float* W3p    = (const float*)d_in[6];
  const float* b3p    = (const float*)d_in[7];
  float* outp = (float*)d_out;

  hipMemsetAsync(outp, 0, (size_t)out_size * sizeof(float), stream);
  ode_mfma_kernel<<<2560, 256, 0, stream>>>(sigmap, Wpp, W1p, b1p, W2p, b2p,
                                            W3p, b3p, outp);
  (void)d_ws; (void)ws_size; (void)n_in; (void)in_sizes;
}

// Round 4
// 337.501 us; speedup vs baseline: 1.3382x; 1.1781x over previous
//
#include <hip/hip_runtime.h>

// ODEDriftIntegrator: 24 RHS evals of a 2->64->64->1 tanh MLP per point,
// Dormand-Prince fixed-step (k7 dead: b7=0). Wave = 16 points via
// mfma_f32_16x16x32_f16 computing W2^T @ H1^T (point index == lane&15 for
// B-operand and D-output; A/B k-convention self-consistent).
//
// R4 (= R3 with type fix): all f16 vectors are __fp16-based to exactly match
// clang's builtin signatures (E2h/V8h). Packed-f16 tanh: degree-9 odd poly
// (Chebyshev, |s|<=3.1; arg pre-halved so Horner runs on w=(s/2)^2 in
// [0,2.4]; the 0.5 is folded into W1/W2/b2). v_pk_fma_f16 = 2 tanh lanes/op,
// zero trans, no bf16 converts. Bias in MFMA C-init. Layer3 via packed-f16
// accumulate (no fdot2 dependence).

typedef __fp16 f16;
typedef __attribute__((ext_vector_type(2))) __fp16 h2;
typedef __attribute__((ext_vector_type(8))) __fp16 h8;
typedef __attribute__((ext_vector_type(4))) float f32x4;

#define NPTS   (131072 * 5)
#define NBATCH (NPTS / 16)          // 40960 batches of 16 points

__device__ __forceinline__ h2 pkrtz(float a, float b) {
  return __builtin_amdgcn_cvt_pkrtz(a, b);   // E2h: exact type match
}
__device__ __forceinline__ h2 hbc(float v) {
  f16 h = (f16)v; h2 r = {h, h}; return r;
}
__device__ __forceinline__ h2 pk_fma(h2 a, h2 b, h2 c) {
#if __has_builtin(__builtin_elementwise_fma)
  return __builtin_elementwise_fma(a, b, c);
#else
  return a * b + c;
#endif
}
__device__ __forceinline__ h2 pk_clamp(h2 x, h2 lo, h2 hi) {
  return __builtin_elementwise_min(__builtin_elementwise_max(x, lo), hi);
}

// tanh(s) with sh = s/2 as input (0.5 pre-folded upstream).
// y = sh * q(sh^2), q quartic (Chebyshev interp of 2*tanh(2t)/(2t), t=sh).
// Valid |sh|<=1.55 (clamped); max err ~0.010 fit + ~0.003 f16 eval.
__device__ __forceinline__ h2 tanh_pk(h2 sh) {
  const h2 LIM = hbc(1.55f);
  const h2 Q0 = hbc(1.975244f), Q1 = hbc(-2.110032f), Q2 = hbc(1.643616f),
           Q3 = hbc(-0.649933f), Q4 = hbc(0.098079f);
  h2 s = pk_clamp(sh, -LIM, LIM);
  h2 w = s * s;
  h2 p = pk_fma(Q4, w, Q3);
  p = pk_fma(p, w, Q2);
  p = pk_fma(p, w, Q1);
  p = pk_fma(p, w, Q0);
  return s * p;
}

union HU { h2 p[4]; h8 v; };

__global__ void ode_mfma_kernel(
    const float* __restrict__ sigmap,  // [NPTS,3]
    const float* __restrict__ Wpp,     // [NPTS]
    const float* __restrict__ W1p,     // [2,64]
    const float* __restrict__ b1p,     // [64]
    const float* __restrict__ W2p,     // [64,64]
    const float* __restrict__ b2p,     // [64]
    const float* __restrict__ W3p,     // [64,1]
    const float* __restrict__ b3p,     // [1]
    float* __restrict__ outp)          // [131072]
{
  const int lane = threadIdx.x & 63;
  const int col  = lane & 15;   // point slot within batch (B-col == D-col)
  const int g    = lane >> 4;   // lane group (k-group / D-row group)
  const int wid  = blockIdx.x * (blockDim.x >> 6) + (threadIdx.x >> 6);
  const int nw   = gridDim.x * (blockDim.x >> 6);

  // ---- persistent per-lane constants ----
  // layer1: element e of B-side: e<8 -> j=8g+e (k-frag 0), e>=8 -> j=32+8g+(e-8)
  // packed pairs ee: ee<4 -> j0=8g+2ee ; ee>=4 -> j0=32+8g+2(ee-4). 0.5 folded.
  h2 w10p[8];
#pragma unroll
  for (int ee = 0; ee < 8; ++ee) {
    int j0 = (ee < 4) ? (8 * g + 2 * ee) : (32 + 8 * g + 2 * (ee - 4));
    w10p[ee] = pkrtz(0.5f * W1p[j0], 0.5f * W1p[j0 + 1]);
  }
  // A-frags = 0.5*W2^T (f16). tile t = out-hidden [16t,16t+16); A-row = col;
  // k element e at group g -> in-hidden kt*32 + 8g + e.
  h8 afr[4][2];
#pragma unroll
  for (int t = 0; t < 4; ++t)
#pragma unroll
    for (int kt = 0; kt < 2; ++kt) {
      HU tmp;
#pragma unroll
      for (int ee = 0; ee < 4; ++ee) {
        int k0 = kt * 32 + 8 * g + 2 * ee;
        tmp.p[ee] = pkrtz(0.5f * W2p[(k0)     * 64 + 16 * t + col],
                          0.5f * W2p[(k0 + 1) * 64 + 16 * t + col]);
      }
      afr[t][kt] = tmp.v;
    }
  // D-side: lane holds out-hidden j = 16t + 4g + r. Bias (x0.5) as MFMA C-init.
  f32x4 cinit[4];
  h2 w3p[8];
#pragma unroll
  for (int t = 0; t < 4; ++t) {
    int jb = 16 * t + 4 * g;
#pragma unroll
    for (int r = 0; r < 4; ++r) cinit[t][r] = 0.5f * b2p[jb + r];
    w3p[2 * t]     = pkrtz(W3p[jb],     W3p[jb + 1]);
    w3p[2 * t + 1] = pkrtz(W3p[jb + 2], W3p[jb + 3]);
  }
  const float b3v = b3p[0];

  // DP coefficients (h pre-multiplied)
  const float h   = 0.0025f;
  const float c21 = h * (1.0f / 5.0f);
  const float c31 = h * (3.0f / 40.0f),      c32 = h * (9.0f / 40.0f);
  const float c41 = h * (44.0f / 45.0f),     c42 = -h * (56.0f / 15.0f),    c43 = h * (32.0f / 9.0f);
  const float c51 = h * (19372.0f / 6561.0f), c52 = -h * (25360.0f / 2187.0f),
              c53 = h * (64448.0f / 6561.0f), c54 = -h * (212.0f / 729.0f);
  const float c61 = h * (9017.0f / 3168.0f),  c62 = -h * (355.0f / 33.0f),
              c63 = h * (46732.0f / 5247.0f), c64 = h * (49.0f / 176.0f),   c65 = -h * (5103.0f / 18656.0f);
  const float d1 = h * (35.0f / 384.0f), d3 = h * (500.0f / 1113.0f), d4 = h * (125.0f / 192.0f),
              d5 = -h * (2187.0f / 6784.0f), d6 = h * (11.0f / 84.0f);

  for (int batch = wid; batch < NBATCH; batch += nw) {
    const int p = batch * 16 + col;
    float x           = sigmap[3 * p + 0];
    const float u     = sigmap[3 * p + 1];
    const float wdiff = sigmap[3 * p + 2];

    // cvp[ee] = 0.5*(u*W1[1][j] + b1[j]) packed (W1/b1 re-read: L1-resident)
    h2 cvp[8];
#pragma unroll
    for (int ee = 0; ee < 8; ++ee) {
      int j0 = (ee < 4) ? (8 * g + 2 * ee) : (32 + 8 * g + 2 * (ee - 4));
      cvp[ee] = pkrtz(0.5f * fmaf(u, W1p[64 + j0],     b1p[j0]),
                      0.5f * fmaf(u, W1p[64 + j0 + 1], b1p[j0 + 1]));
    }

    auto rhs = [&](float xi) -> float {
      h2 xh = pkrtz(xi, xi);
      // layer1: 16 tanh (packed) -> two B-frags (H1^T) directly in f16
      HU b0, b1f;
#pragma unroll
      for (int ee = 0; ee < 4; ++ee) {
        b0.p[ee]  = tanh_pk(pk_fma(xh, w10p[ee],     cvp[ee]));
        b1f.p[ee] = tanh_pk(pk_fma(xh, w10p[ee + 4], cvp[ee + 4]));
      }
      // layer2 (MFMA, bias in C-init) + epilogue tanh + layer3 packed dot
      h2 ph = hbc(0.0f);
#pragma unroll
      for (int t = 0; t < 4; ++t) {
        f32x4 acc = cinit[t];
        acc = __builtin_amdgcn_mfma_f32_16x16x32_f16(afr[t][0], b0.v,  acc, 0, 0, 0);
        acc = __builtin_amdgcn_mfma_f32_16x16x32_f16(afr[t][1], b1f.v, acc, 0, 0, 0);
        h2 th0 = tanh_pk(pkrtz(acc[0], acc[1]));
        h2 th1 = tanh_pk(pkrtz(acc[2], acc[3]));
        ph = pk_fma(th0, w3p[2 * t],     ph);
        ph = pk_fma(th1, w3p[2 * t + 1], ph);
      }
      float partial = (float)ph[0] + (float)ph[1];
      // sum the 4 k-groups (same col, g=0..3)
      partial += __shfl_xor(partial, 16, 64);
      partial += __shfl_xor(partial, 32, 64);
      return partial + b3v;
    };

#pragma unroll 1
    for (int step = 0; step < 4; ++step) {
      float k1 = rhs(x);
      float k2 = rhs(fmaf(c21, k1, x));
      float k3 = rhs(fmaf(c32, k2, fmaf(c31, k1, x)));
      float k4 = rhs(fmaf(c43, k3, fmaf(c42, k2, fmaf(c41, k1, x))));
      float k5 = rhs(fmaf(c54, k4, fmaf(c53, k3, fmaf(c52, k2, fmaf(c51, k1, x)))));
      float k6 = rhs(fmaf(c65, k5, fmaf(c64, k4, fmaf(c63, k3, fmaf(c62, k2, fmaf(c61, k1, x))))));
      x = fmaf(d6, k6, fmaf(d5, k5, fmaf(d4, k4, fmaf(d3, k3, fmaf(d1, k1, x)))));
    }

    x = fmaf(0.01f, wdiff, x);  // diffusion kick: sqrt(2*0.5*sigma^2*dt) = 0.01

    if (lane < 16) {  // one replica writes
      atomicAdd(&outp[p / 5], Wpp[p] * x);
    }
  }
}

extern "C" void kernel_launch(void* const* d_in, const int* in_sizes, int n_in,
                              void* d_out, int out_size, void* d_ws, size_t ws_size,
                              hipStream_t stream) {
  const float* sigmap = (const float*)d_in[0];
  const float* Wpp    = (const float*)d_in[1];
  const float* W1p    = (const float*)d_in[2];
  const float* b1p    = (const float*)d_in[3];
  const float* W2p    = (const float*)d_in[4];
  const float* b2p    = (const float*)d_in[5];
  const float* W3p    = (const float*)d_in[6];
  const float* b3p    = (const float*)d_in[7];
  float* outp = (float*)d_out;

  (void)hipMemsetAsync(outp, 0, (size_t)out_size * sizeof(float), stream);
  ode_mfma_kernel<<<2560, 256, 0, stream>>>(sigmap, Wpp, W1p, b1p, W2p, b2p,
                                            W3p, b3p, outp);
  (void)d_ws; (void)ws_size; (void)n_in; (void)in_sizes;
}